// Round 5
// baseline (396.574 us; speedup 1.0000x reference)
//
#include <hip/hip_runtime.h>
#include <hip/hip_bf16.h>

// Problem constants: x [B,C,H,W] = [4,512,64,64], N = H*W = 4096, 32 groups.
#define B_ 4
#define C_ 512
#define N_ 4096
#define G_ 32
#define CPG_ 16

typedef __bf16 bf16;
using bf16x4 = __attribute__((ext_vector_type(4))) __bf16;
using bf16x8 = __attribute__((ext_vector_type(8))) __bf16;
using f32x4  = __attribute__((ext_vector_type(4))) float;

// ---------------------------------------------------------------- GroupNorm
__global__ __launch_bounds__(256) void gn_stats(const float* __restrict__ x,
                                                float* __restrict__ mv,
                                                float* __restrict__ rv) {
    __shared__ float r1[4], r2[4];
    const int bg = blockIdx.x;                    // b*32+g ; group channels contiguous
    const float* xg = x + (long)bg * (CPG_ * N_);
    const int tid = threadIdx.x;
    float s = 0.f, ss = 0.f;
    for (int i = tid; i < CPG_ * N_ / 4; i += 256) {
        f32x4 v = ((const f32x4*)xg)[i];
#pragma unroll
        for (int j = 0; j < 4; ++j) { s += v[j]; ss += v[j] * v[j]; }
    }
#pragma unroll
    for (int o = 32; o > 0; o >>= 1) { s += __shfl_down(s, o); ss += __shfl_down(ss, o); }
    if ((tid & 63) == 0) { r1[tid >> 6] = s; r2[tid >> 6] = ss; }
    __syncthreads();
    if (tid == 0) {
        float S = r1[0] + r1[1] + r1[2] + r1[3];
        float SS = r2[0] + r2[1] + r2[2] + r2[3];
        float mean = S / (CPG_ * N_);
        float var = SS / (CPG_ * N_) - mean * mean;
        mv[bg] = mean;
        rv[bg] = rsqrtf(var + 1e-6f);
    }
}

// normalize + transpose: x [B,C,N] f32 -> ht [B,N,C] bf16 (64x64 tiles via LDS)
__global__ __launch_bounds__(256) void gn_apply(const float* __restrict__ x,
                                                const float* __restrict__ mv,
                                                const float* __restrict__ rv,
                                                const float* __restrict__ gamma,
                                                const float* __restrict__ beta,
                                                bf16* __restrict__ ht) {
    __shared__ float tile[64][65];
    const int b = blockIdx.z, c0 = blockIdx.y * 64, n0 = blockIdx.x * 64;
    const int tid = threadIdx.x;
    const int rr = tid >> 4, cc4 = (tid & 15) * 4;
    const float* xb = x + ((long)b * C_ + c0) * N_ + n0;
#pragma unroll
    for (int p2 = 0; p2 < 4; ++p2) {
        const int cl = p2 * 16 + rr;
        const int g = (c0 + cl) >> 4;
        const float m = mv[b * G_ + g], rs = rv[b * G_ + g];
        const float ga = gamma[c0 + cl], be = beta[c0 + cl];
        f32x4 v = *(const f32x4*)&xb[(long)cl * N_ + cc4];
#pragma unroll
        for (int j = 0; j < 4; ++j) tile[cl][cc4 + j] = (v[j] - m) * rs * ga + be;
    }
    __syncthreads();
    bf16* hb = ht + ((long)b * N_ + n0) * C_ + c0;
#pragma unroll
    for (int p2 = 0; p2 < 4; ++p2) {
        const int nn = p2 * 16 + rr;
        bf16x4 o4 = { (bf16)tile[cc4 + 0][nn], (bf16)tile[cc4 + 1][nn],
                      (bf16)tile[cc4 + 2][nn], (bf16)tile[cc4 + 3][nn] };
        *(bf16x4*)&hb[(long)nn * C_ + cc4] = o4;
    }
}

// ---------------------------------------------------------------- f32 -> bf16 (4 weights, one dispatch)
__global__ __launch_bounds__(256) void f2b4(const float* __restrict__ w0, const float* __restrict__ w1,
                                            const float* __restrict__ w2, const float* __restrict__ w3,
                                            bf16* __restrict__ o0, bf16* __restrict__ o1,
                                            bf16* __restrict__ o2, bf16* __restrict__ o3, int n4) {
    const float* in = (blockIdx.y == 0) ? w0 : (blockIdx.y == 1) ? w1 : (blockIdx.y == 2) ? w2 : w3;
    bf16* o = (blockIdx.y == 0) ? o0 : (blockIdx.y == 1) ? o1 : (blockIdx.y == 2) ? o2 : o3;
    int i = blockIdx.x * 256 + threadIdx.x;
    if (i < n4) {
        f32x4 v = ((const f32x4*)in)[i];
        bf16x4 r = { (bf16)v[0], (bf16)v[1], (bf16)v[2], (bf16)v[3] };
        ((bf16x4*)o)[i] = r;
    }
}

// ---------------------------------------------------------------- GEMM
// out[M,N] = scale * A[M,K] @ Bt[N,K]^T (+bias +resid). 128x128 tile, BK=32,
// 4 waves each own a 64x64 quadrant (4x4 frags of mfma_f32_16x16x32_bf16).
// K-loop: double-buffered LDS, single barrier per K-step, stage issued FIRST
// so global->LDS latency hides under ds_read+MFMA of the current tile (T3-min).
// Safety: iter i stages buf[(i+1)&1]; its previous readers (tile i-1) finished
// before iter i-1's ending __syncthreads (which also drained tile i's loads).
// GRIDSWAP: blockIdx.x walks M (rows) -> consecutive blocks share the B-panel.
// EXPSUM:   epilogue writes exp(min(s*scale,60)) bf16 + per-block row partial
//           sums to rowpart[(z*M+row)*gridDim.x + blockIdx.x] (softmax fused).
// INVSUM:   epilogue multiplies acc rows by invsum[z*M+row] (softmax denom).
// DUAL:     (GRIDSWAP only) blockIdx.y >= gridDim.y/2 selects {Bt2,bias2,outp2}.
template <int OUTF32, int BIASMODE /*0 none,1 col,2 row*/, int RESID, int GRIDSWAP,
          int EXPSUM, int INVSUM, int DUAL>
__global__ __launch_bounds__(256, 2)
void gemm_bt(const bf16* __restrict__ A, const bf16* __restrict__ Bt,
             void* __restrict__ outp, const float* __restrict__ bias,
             const float* __restrict__ resid,
             float* __restrict__ rowpart, const float* __restrict__ invsum,
             const bf16* __restrict__ Bt2, const float* __restrict__ bias2,
             void* __restrict__ outp2,
             int M, int N, int K, float scale,
             long aStride, long btStride, long outStride, long residStride) {
    __shared__ __align__(16) bf16 lA[2][128 * 32];
    __shared__ __align__(16) bf16 lB[2][128 * 32];

    const int tid = threadIdx.x;
    const int wid = tid >> 6;
    const int lane = tid & 63;
    const int z = blockIdx.z;
    A += (long)z * aStride;
    Bt += (long)z * btStride;
    int ybn = GRIDSWAP ? blockIdx.y : blockIdx.x;
    if (DUAL) {
        const int half = gridDim.y >> 1;
        if (ybn >= half) { ybn -= half; Bt = Bt2; bias = bias2; outp = outp2; }
    }
    const int bm = (GRIDSWAP ? blockIdx.x : blockIdx.y) * 128;
    const int bn = ybn * 128;
    const int wr = (wid >> 1) * 64;
    const int wc = (wid & 1) * 64;

    f32x4 acc[4][4];
#pragma unroll
    for (int m = 0; m < 4; ++m)
#pragma unroll
        for (int n = 0; n < 4; ++n) acc[m][n] = (f32x4){0.f, 0.f, 0.f, 0.f};

    const int srow = lane >> 2;           // staging: 16 rows x 64B per wave-chunk
    const int skcol = (lane & 3) * 8;
    const int lr = lane >> 4;             // frag k-group / C row-group
    const int lc = lane & 15;             // frag row (A) / col (B,C)

    auto stage = [&](int buf, int k0) {
#pragma unroll
        for (int c = 0; c < 2; ++c) {
            const int chunk = wid * 2 + c;          // 0..7
            const int row = chunk * 16 + srow;      // 0..127
            const bf16* gA = A + (long)(bm + row) * K + (k0 + skcol);
            const bf16* gB = Bt + (long)(bn + row) * K + (k0 + skcol);
            __builtin_amdgcn_global_load_lds(
                (const __attribute__((address_space(1))) void*)gA,
                (__attribute__((address_space(3))) void*)&lA[buf][chunk * 512], 16, 0, 0);
            __builtin_amdgcn_global_load_lds(
                (const __attribute__((address_space(1))) void*)gB,
                (__attribute__((address_space(3))) void*)&lB[buf][chunk * 512], 16, 0, 0);
        }
    };

    const int nk = K >> 5;
    stage(0, 0);
    __syncthreads();                      // drains tile 0; all waves aligned
    for (int i = 0; i < nk; ++i) {
        if (i + 1 < nk) stage((i + 1) & 1, (i + 1) << 5);   // async, overlapped
        const int cur = i & 1;
        bf16x8 aF[4], bF[4];
#pragma unroll
        for (int m = 0; m < 4; ++m)
            aF[m] = *(const bf16x8*)&lA[cur][(wr + m * 16 + lc) * 32 + lr * 8];
#pragma unroll
        for (int n = 0; n < 4; ++n)
            bF[n] = *(const bf16x8*)&lB[cur][(wc + n * 16 + lc) * 32 + lr * 8];
#pragma unroll
        for (int m = 0; m < 4; ++m)
#pragma unroll
            for (int n = 0; n < 4; ++n)
                acc[m][n] = __builtin_amdgcn_mfma_f32_16x16x32_bf16(aF[m], bF[n],
                                                                    acc[m][n], 0, 0, 0);
        __syncthreads();                  // drains tile i+1 loads; frees buf cur
    }

    if constexpr (EXPSUM) {
        // exp + per-block row partial sums (softmax numerator fused into GEMM).
        __shared__ float rsum[2][128];
        bf16* outB = (bf16*)outp + (long)z * outStride;
        float s_mj[4][4];
#pragma unroll
        for (int m = 0; m < 4; ++m)
#pragma unroll
            for (int j = 0; j < 4; ++j) s_mj[m][j] = 0.f;
#pragma unroll
        for (int m = 0; m < 4; ++m)
#pragma unroll
            for (int n = 0; n < 4; ++n) {
                const int gc = bn + wc + n * 16 + lc;
#pragma unroll
                for (int j = 0; j < 4; ++j) {
                    const int gr = bm + wr + m * 16 + lr * 4 + j;
                    float e = __expf(fminf(acc[m][n][j] * scale, 60.f));
                    outB[(long)gr * N + gc] = (bf16)e;
                    s_mj[m][j] += e;
                }
            }
        // reduce across the 16 lanes sharing lr (they hold the same rows)
#pragma unroll
        for (int m = 0; m < 4; ++m)
#pragma unroll
            for (int j = 0; j < 4; ++j)
#pragma unroll
                for (int o = 1; o < 16; o <<= 1)
                    s_mj[m][j] += __shfl_xor(s_mj[m][j], o);
        if (lc == 0) {
#pragma unroll
            for (int m = 0; m < 4; ++m)
#pragma unroll
                for (int j = 0; j < 4; ++j)
                    rsum[wc >> 6][wr + m * 16 + lr * 4 + j] = s_mj[m][j];
        }
        __syncthreads();
        if (tid < 128) {
            float p = rsum[0][tid] + rsum[1][tid];
            rowpart[((long)z * M + bm + tid) * gridDim.x + blockIdx.x] = p;
        }
        return;
    }

    float invs[4][4];
    if constexpr (INVSUM) {
#pragma unroll
        for (int m = 0; m < 4; ++m)
#pragma unroll
            for (int j = 0; j < 4; ++j)
                invs[m][j] = invsum[(long)z * M + bm + wr + m * 16 + lr * 4 + j];
    }

    float* outF = (float*)outp + (long)z * outStride;
    bf16* outB = (bf16*)outp + (long)z * outStride;
    const float* res = resid + (long)z * residStride;
#pragma unroll
    for (int m = 0; m < 4; ++m) {
#pragma unroll
        for (int n = 0; n < 4; ++n) {
            const int gc = bn + wc + n * 16 + lc;
            float cb = (BIASMODE == 1) ? bias[gc] : 0.f;
#pragma unroll
            for (int j = 0; j < 4; ++j) {
                const int gr = bm + wr + m * 16 + lr * 4 + j;
                float v = INVSUM ? acc[m][n][j] * invs[m][j]
                                 : acc[m][n][j] * scale + cb;
                if (BIASMODE == 2) v += bias[gr];
                long idx = (long)gr * N + gc;
                if (RESID) v += res[idx];
                if (OUTF32) outF[idx] = v;
                else        outB[idx] = (bf16)v;
            }
        }
    }
}

// ---------------------------------------------------------------- row-sum finalize
__global__ __launch_bounds__(256) void rowinv(const float* __restrict__ rowpart,
                                              float* __restrict__ invsum, int nblk) {
    const int row = blockIdx.x * 256 + threadIdx.x;
    const float* rp = rowpart + (long)row * nblk;
    float s = 0.f;
    for (int i = 0; i < nblk; ++i) s += rp[i];
    invsum[row] = 1.f / s;
}

// ---------------------------------------------------------------- launch
extern "C" void kernel_launch(void* const* d_in, const int* in_sizes, int n_in,
                              void* d_out, int out_size, void* d_ws, size_t ws_size,
                              hipStream_t stream) {
    const float* x     = (const float*)d_in[0];
    const float* gamma = (const float*)d_in[1];
    const float* beta  = (const float*)d_in[2];
    const float* wq = (const float*)d_in[3]; const float* bq = (const float*)d_in[4];
    const float* wk = (const float*)d_in[5]; const float* bk = (const float*)d_in[6];
    const float* wv = (const float*)d_in[7]; const float* bv = (const float*)d_in[8];
    const float* wp = (const float*)d_in[9]; const float* bp = (const float*)d_in[10];

    char* w = (char*)d_ws;
    size_t off = 0;
    auto take = [&](size_t bytes) -> void* {
        void* pp = w + off;
        off += (bytes + 255) & ~(size_t)255;
        return pp;
    };
    float* mv = (float*)take(B_ * G_ * 4);
    float* rv = (float*)take(B_ * G_ * 4);
    bf16* wqb = (bf16*)take((size_t)C_ * C_ * 2);
    bf16* wkb = (bf16*)take((size_t)C_ * C_ * 2);
    bf16* wvb = (bf16*)take((size_t)C_ * C_ * 2);
    bf16* wpb = (bf16*)take((size_t)C_ * C_ * 2);
    bf16* ht  = (bf16*)take((size_t)B_ * N_ * C_ * 2);  // [B,N,C]
    bf16* qt  = (bf16*)take((size_t)B_ * N_ * C_ * 2);  // [B,N,C]
    bf16* kt  = (bf16*)take((size_t)B_ * N_ * C_ * 2);  // [B,N,C]
    bf16* vv  = (bf16*)take((size_t)B_ * C_ * N_ * 2);  // [B,C,N]
    bf16* at  = ht;  // alias: ht dead after v-GEMM, at written by PV afterwards
    float* rowpart = (float*)take((size_t)B_ * N_ * 32 * 4);  // 2 MB row partials
    float* invsum  = (float*)take((size_t)B_ * N_ * 4);       // 64 KB

    // common usage: 1024 + 4*524288 + 4*16777216 + 2097152 + 65536 = 71,369,728.
    // Tier A adds bf16 exp-scores for all batches: + B*N*N*2 = 134,217,728
    //   -> threshold 205,587,456. Pair fallback adds 2*N*N*2 = 67,108,864
    //   -> 138,478,592 (fits: rounds 1-3 ran with >=186.6 MB usage).
    const bool tierA = ws_size >= 205587456ULL;

    gn_stats<<<dim3(B_ * G_), 256, 0, stream>>>(x, mv, rv);
    gn_apply<<<dim3(N_ / 64, C_ / 64, B_), 256, 0, stream>>>(x, mv, rv, gamma, beta, ht);
    f2b4<<<dim3(C_ * C_ / 4 / 256, 4), 256, 0, stream>>>(wq, wk, wv, wp, wqb, wkb, wvb, wpb,
                                                         C_ * C_ / 4);

    // q^T AND k^T in one dispatch (DUAL): 1024 blocks, GRIDSWAP walks rows.
    gemm_bt<0, 1, 0, 1, 0, 0, 1><<<dim3(B_ * N_ / 128, 2 * C_ / 128, 1), 256, 0, stream>>>(
        ht, wqb, qt, bq, nullptr, nullptr, nullptr, wkb, bk, kt,
        B_ * N_, C_, C_, 1.f, 0, 0, 0, 0);
    // v = Wv @ h : [C,N] per batch (z-grid)
    gemm_bt<0, 2, 0, 0, 0, 0, 0><<<dim3(N_ / 128, C_ / 128, B_), 256, 0, stream>>>(
        wvb, ht, vv, bv, nullptr, nullptr, nullptr, nullptr, nullptr, nullptr,
        C_, N_, C_, 1.f, 0, (long)N_ * C_, (long)C_ * N_, 0);

    const float scl = 0.044194173824159216f;  // 1/sqrt(512)
    if (tierA) {
        bf16* sc = (bf16*)take((size_t)B_ * N_ * N_ * 2);
        // scores -> exp(scores) bf16 + row partial sums, all batches (4096 blocks)
        gemm_bt<0, 0, 0, 0, 1, 0, 0><<<dim3(N_ / 128, N_ / 128, B_), 256, 0, stream>>>(
            qt, kt, sc, nullptr, nullptr, rowpart, nullptr, nullptr, nullptr, nullptr,
            N_, N_, C_, scl, (long)N_ * C_, (long)N_ * C_, (long)N_ * N_, 0);
        rowinv<<<dim3(B_ * N_ / 256), 256, 0, stream>>>(rowpart, invsum, N_ / 128);
        // PV with fused 1/rowsum: 512 blocks; GRIDSWAP so exp-scores fetched once
        gemm_bt<0, 0, 0, 1, 0, 1, 0><<<dim3(N_ / 128, C_ / 128, B_), 256, 0, stream>>>(
            sc, vv, at, nullptr, nullptr, nullptr, invsum, nullptr, nullptr, nullptr,
            N_, C_, N_, 1.f, (long)N_ * N_, (long)C_ * N_, (long)N_ * C_, 0);
    } else {
        bf16* sc = (bf16*)take((size_t)2 * N_ * N_ * 2);
        for (int p = 0; p < 2; ++p) {
            const long o2 = (long)p * 2 * N_ * C_;
            gemm_bt<0, 0, 0, 0, 1, 0, 0><<<dim3(N_ / 128, N_ / 128, 2), 256, 0, stream>>>(
                qt + o2, kt + o2, sc, nullptr, nullptr, rowpart, nullptr, nullptr,
                nullptr, nullptr, N_, N_, C_, scl,
                (long)N_ * C_, (long)N_ * C_, (long)N_ * N_, 0);
            rowinv<<<dim3(2 * N_ / 256), 256, 0, stream>>>(rowpart, invsum, N_ / 128);
            gemm_bt<0, 0, 0, 1, 0, 1, 0><<<dim3(N_ / 128, C_ / 128, 2), 256, 0, stream>>>(
                sc, vv + o2, at + o2, nullptr, nullptr, nullptr, invsum, nullptr,
                nullptr, nullptr, N_, C_, N_, 1.f,
                (long)N_ * N_, (long)C_ * N_, (long)N_ * C_, 0);
        }
    }
    // out = x + Wp @ a + bp : [C,N] per batch, fused residual
    gemm_bt<1, 2, 1, 0, 0, 0, 0><<<dim3(N_ / 128, C_ / 128, B_), 256, 0, stream>>>(
        wpb, at, d_out, bp, x, nullptr, nullptr, nullptr, nullptr, nullptr,
        C_, N_, C_, 1.f, 0, (long)N_ * C_, (long)C_ * N_, (long)C_ * N_);
}

// Round 8
// 376.678 us; speedup vs baseline: 1.0528x; 1.0528x over previous
//
#include <hip/hip_runtime.h>
#include <hip/hip_bf16.h>

// Problem constants: x [B,C,H,W] = [4,512,64,64], N = H*W = 4096, 32 groups.
#define B_ 4
#define C_ 512
#define N_ 4096
#define G_ 32
#define CPG_ 16

typedef __bf16 bf16;
using bf16x4 = __attribute__((ext_vector_type(4))) __bf16;
using bf16x8 = __attribute__((ext_vector_type(8))) __bf16;
using f32x4  = __attribute__((ext_vector_type(4))) float;

// ---------------------------------------------------------------- GroupNorm stats (2-stage)
// stage 1: 8 segments per (b,g) group -> 1024 blocks of partial {sum, sumsq}.
__global__ __launch_bounds__(256) void gn_stats_part(const float* __restrict__ x,
                                                     float2* __restrict__ pp) {
    __shared__ float r1[4], r2[4];
    const int bg = blockIdx.y, seg = blockIdx.x;
    const float* xg = x + (long)bg * (CPG_ * N_) + (long)seg * (CPG_ * N_ / 8);
    const int tid = threadIdx.x;
    float s = 0.f, ss = 0.f;
    for (int i = tid; i < CPG_ * N_ / 8 / 4; i += 256) {
        f32x4 v = ((const f32x4*)xg)[i];
#pragma unroll
        for (int j = 0; j < 4; ++j) { s += v[j]; ss += v[j] * v[j]; }
    }
#pragma unroll
    for (int o = 32; o > 0; o >>= 1) { s += __shfl_down(s, o); ss += __shfl_down(ss, o); }
    if ((tid & 63) == 0) { r1[tid >> 6] = s; r2[tid >> 6] = ss; }
    __syncthreads();
    if (tid == 0) {
        float2 out;
        out.x = r1[0] + r1[1] + r1[2] + r1[3];
        out.y = r2[0] + r2[1] + r2[2] + r2[3];
        pp[bg * 8 + seg] = out;
    }
}

// normalize + transpose: x [B,C,N] f32 -> ht [B,N,C] bf16 (64x64 tiles via LDS).
// Finalizes group stats from pp inline (4 groups per block, threads 0-3).
__global__ __launch_bounds__(256) void gn_apply(const float* __restrict__ x,
                                                const float2* __restrict__ pp,
                                                const float* __restrict__ gamma,
                                                const float* __restrict__ beta,
                                                bf16* __restrict__ ht) {
    __shared__ float tile[64][65];
    __shared__ float sm[4], srs[4];
    const int b = blockIdx.z, c0 = blockIdx.y * 64, n0 = blockIdx.x * 64;
    const int tid = threadIdx.x;
    const int rr = tid >> 4, cc4 = (tid & 15) * 4;
    if (tid < 4) {
        const int g = (c0 >> 4) + tid;
        float s = 0.f, ss = 0.f;
#pragma unroll
        for (int u = 0; u < 8; ++u) {
            float2 t = pp[(b * G_ + g) * 8 + u];
            s += t.x; ss += t.y;
        }
        const float mean = s / (CPG_ * N_);
        const float var = ss / (CPG_ * N_) - mean * mean;
        sm[tid] = mean;
        srs[tid] = rsqrtf(var + 1e-6f);
    }
    __syncthreads();
    const float* xb = x + ((long)b * C_ + c0) * N_ + n0;
#pragma unroll
    for (int p2 = 0; p2 < 4; ++p2) {
        const int cl = p2 * 16 + rr;
        const float m = sm[cl >> 4], rs = srs[cl >> 4];
        const float ga = gamma[c0 + cl], be = beta[c0 + cl];
        f32x4 v = *(const f32x4*)&xb[(long)cl * N_ + cc4];
#pragma unroll
        for (int j = 0; j < 4; ++j) tile[cl][cc4 + j] = (v[j] - m) * rs * ga + be;
    }
    __syncthreads();
    bf16* hb = ht + ((long)b * N_ + n0) * C_ + c0;
#pragma unroll
    for (int p2 = 0; p2 < 4; ++p2) {
        const int nn = p2 * 16 + rr;
        bf16x4 o4 = { (bf16)tile[cc4 + 0][nn], (bf16)tile[cc4 + 1][nn],
                      (bf16)tile[cc4 + 2][nn], (bf16)tile[cc4 + 3][nn] };
        *(bf16x4*)&hb[(long)nn * C_ + cc4] = o4;
    }
}

// ---------------------------------------------------------------- f32 -> bf16 (4 weights, one dispatch)
__global__ __launch_bounds__(256) void f2b4(const float* __restrict__ w0, const float* __restrict__ w1,
                                            const float* __restrict__ w2, const float* __restrict__ w3,
                                            bf16* __restrict__ o0, bf16* __restrict__ o1,
                                            bf16* __restrict__ o2, bf16* __restrict__ o3, int n4) {
    const float* in = (blockIdx.y == 0) ? w0 : (blockIdx.y == 1) ? w1 : (blockIdx.y == 2) ? w2 : w3;
    bf16* o = (blockIdx.y == 0) ? o0 : (blockIdx.y == 1) ? o1 : (blockIdx.y == 2) ? o2 : o3;
    int i = blockIdx.x * 256 + threadIdx.x;
    if (i < n4) {
        f32x4 v = ((const f32x4*)in)[i];
        bf16x4 r = { (bf16)v[0], (bf16)v[1], (bf16)v[2], (bf16)v[3] };
        ((bf16x4*)o)[i] = r;
    }
}

// ---------------------------------------------------------------- GEMM
// out[M,N] = scale * A[M,K] @ Bt[N,K]^T (+bias +resid). Block tile BM x BN with
// BM = 32*WRM, BN = 32*WCN; 4 waves in a 2x2 grid, each owns (16*WRM)x(16*WCN)
// via WRMxWCN frags of mfma_f32_16x16x32_bf16. BK=32.
// DBUF=1: double-buffered LDS, 1 barrier/K-step (neutral-to-better for long K).
// GRIDSWAP: blockIdx.x walks M (rows) -> consecutive blocks share the B-panel.
// EXPSUM:   epilogue writes exp(min(s*scale,60)) bf16 + per-block row partial
//           sums to rowpart[(z*M+row)*gridDim.x + blockIdx.x] (softmax fused).
// INVSUM:   epilogue multiplies acc rows by invsum[z*M+row] (softmax denom).
// DUAL:     (GRIDSWAP only) blockIdx.y >= gridDim.y/2 selects {Bt2,bias2,outp2}.
template <int WRM, int WCN, int OUTF32, int BIASMODE /*0 none,1 col,2 row*/,
          int RESID, int GRIDSWAP, int EXPSUM, int INVSUM, int DUAL, int DBUF>
__global__ __launch_bounds__(256, 2)
void gemm_bt(const bf16* __restrict__ A, const bf16* __restrict__ Bt,
             void* __restrict__ outp, const float* __restrict__ bias,
             const float* __restrict__ resid,
             float* __restrict__ rowpart, const float* __restrict__ invsum,
             const bf16* __restrict__ Bt2, const float* __restrict__ bias2,
             void* __restrict__ outp2,
             int M, int N, int K, float scale,
             long aStride, long btStride, long outStride, long residStride) {
    constexpr int BM = 32 * WRM, BN = 32 * WCN;
    constexpr int CHA = BM / 16, CHB = BN / 16, TOT = CHA + CHB;
    static_assert(TOT % 4 == 0, "chunk count must divide across 4 waves");
    __shared__ __align__(16) bf16 lA[DBUF + 1][BM * 32];
    __shared__ __align__(16) bf16 lB[DBUF + 1][BN * 32];

    const int tid = threadIdx.x;
    const int wid = tid >> 6;
    const int lane = tid & 63;
    const int z = blockIdx.z;
    A += (long)z * aStride;
    Bt += (long)z * btStride;
    int ybn = GRIDSWAP ? blockIdx.y : blockIdx.x;
    if (DUAL) {
        const int half = gridDim.y >> 1;
        if (ybn >= half) { ybn -= half; Bt = Bt2; bias = bias2; outp = outp2; }
    }
    const int bm = (GRIDSWAP ? blockIdx.x : blockIdx.y) * BM;
    const int bn = ybn * BN;
    const int wr = (wid >> 1) * 16 * WRM;
    const int wc = (wid & 1) * 16 * WCN;

    f32x4 acc[WRM][WCN];
#pragma unroll
    for (int m = 0; m < WRM; ++m)
#pragma unroll
        for (int n = 0; n < WCN; ++n) acc[m][n] = (f32x4){0.f, 0.f, 0.f, 0.f};

    const int srow = lane >> 2;           // staging: 16 rows x 64B per chunk
    const int skcol = (lane & 3) * 8;
    const int lr = lane >> 4;             // frag k-group / C row-group
    const int lc = lane & 15;             // frag row (A) / col (B,C)

    auto stage = [&](int buf, int k0) {
#pragma unroll
        for (int u = 0; u < TOT / 4; ++u) {
            const int c = wid + u * 4;
            if (c < CHA) {
                const int row = c * 16 + srow;
                const bf16* gA = A + (long)(bm + row) * K + (k0 + skcol);
                __builtin_amdgcn_global_load_lds(
                    (const __attribute__((address_space(1))) void*)gA,
                    (__attribute__((address_space(3))) void*)&lA[buf][c * 512], 16, 0, 0);
            } else {
                const int c2 = c - CHA;
                const int row = c2 * 16 + srow;
                const bf16* gB = Bt + (long)(bn + row) * K + (k0 + skcol);
                __builtin_amdgcn_global_load_lds(
                    (const __attribute__((address_space(1))) void*)gB,
                    (__attribute__((address_space(3))) void*)&lB[buf][c2 * 512], 16, 0, 0);
            }
        }
    };

    auto compute = [&](int cur) {
        bf16x8 aF[WRM], bF[WCN];
#pragma unroll
        for (int m = 0; m < WRM; ++m)
            aF[m] = *(const bf16x8*)&lA[cur][(wr + m * 16 + lc) * 32 + lr * 8];
#pragma unroll
        for (int n = 0; n < WCN; ++n)
            bF[n] = *(const bf16x8*)&lB[cur][(wc + n * 16 + lc) * 32 + lr * 8];
#pragma unroll
        for (int m = 0; m < WRM; ++m)
#pragma unroll
            for (int n = 0; n < WCN; ++n)
                acc[m][n] = __builtin_amdgcn_mfma_f32_16x16x32_bf16(aF[m], bF[n],
                                                                    acc[m][n], 0, 0, 0);
    };

    const int nk = K >> 5;
    if (DBUF) {
        stage(0, 0);
        __syncthreads();
        for (int i = 0; i < nk; ++i) {
            if (i + 1 < nk) stage((i + 1) & 1, (i + 1) << 5);
            compute(i & 1);
            __syncthreads();
        }
    } else {
        for (int i = 0; i < nk; ++i) {
            stage(0, i << 5);
            __syncthreads();
            compute(0);
            __syncthreads();
        }
    }

    if constexpr (EXPSUM) {
        // exp + per-block row partial sums (softmax numerator fused into GEMM).
        __shared__ float rsum[2][BM];
        bf16* outB = (bf16*)outp + (long)z * outStride;
        float s_mj[WRM][4];
#pragma unroll
        for (int m = 0; m < WRM; ++m)
#pragma unroll
            for (int j = 0; j < 4; ++j) s_mj[m][j] = 0.f;
#pragma unroll
        for (int m = 0; m < WRM; ++m)
#pragma unroll
            for (int n = 0; n < WCN; ++n) {
                const int gc = bn + wc + n * 16 + lc;
#pragma unroll
                for (int j = 0; j < 4; ++j) {
                    const int gr = bm + wr + m * 16 + lr * 4 + j;
                    float e = __expf(fminf(acc[m][n][j] * scale, 60.f));
                    outB[(long)gr * N + gc] = (bf16)e;
                    s_mj[m][j] += e;
                }
            }
        // reduce across the 16 lanes sharing lr (they hold the same rows)
#pragma unroll
        for (int m = 0; m < WRM; ++m)
#pragma unroll
            for (int j = 0; j < 4; ++j)
#pragma unroll
                for (int o = 1; o < 16; o <<= 1)
                    s_mj[m][j] += __shfl_xor(s_mj[m][j], o);
        if (lc == 0) {
#pragma unroll
            for (int m = 0; m < WRM; ++m)
#pragma unroll
                for (int j = 0; j < 4; ++j)
                    rsum[wid & 1][wr + m * 16 + lr * 4 + j] = s_mj[m][j];
        }
        __syncthreads();
        if (tid < BM) {
            float p = rsum[0][tid] + rsum[1][tid];
            rowpart[((long)z * M + bm + tid) * gridDim.x + blockIdx.x] = p;
        }
        return;
    }

    float invs[WRM][4];
    if constexpr (INVSUM) {
#pragma unroll
        for (int m = 0; m < WRM; ++m)
#pragma unroll
            for (int j = 0; j < 4; ++j)
                invs[m][j] = invsum[(long)z * M + bm + wr + m * 16 + lr * 4 + j];
    }

    float* outF = (float*)outp + (long)z * outStride;
    bf16* outB = (bf16*)outp + (long)z * outStride;
    const float* res = resid + (long)z * residStride;
#pragma unroll
    for (int m = 0; m < WRM; ++m) {
#pragma unroll
        for (int n = 0; n < WCN; ++n) {
            const int gc = bn + wc + n * 16 + lc;
            float cb = (BIASMODE == 1) ? bias[gc] : 0.f;
#pragma unroll
            for (int j = 0; j < 4; ++j) {
                const int gr = bm + wr + m * 16 + lr * 4 + j;
                float v = INVSUM ? acc[m][n][j] * invs[m][j]
                                 : acc[m][n][j] * scale + cb;
                if (BIASMODE == 2) v += bias[gr];
                long idx = (long)gr * N + gc;
                if (RESID) v += res[idx];
                if (OUTF32) outF[idx] = v;
                else        outB[idx] = (bf16)v;
            }
        }
    }
}

// ---------------------------------------------------------------- row-sum finalize
__global__ __launch_bounds__(256) void rowinv(const float* __restrict__ rowpart,
                                              float* __restrict__ invsum, int nblk) {
    const int row = blockIdx.x * 256 + threadIdx.x;
    const float* rp = rowpart + (long)row * nblk;
    float s = 0.f;
    for (int i = 0; i < nblk; ++i) s += rp[i];
    invsum[row] = 1.f / s;
}

// ---------------------------------------------------------------- launch
extern "C" void kernel_launch(void* const* d_in, const int* in_sizes, int n_in,
                              void* d_out, int out_size, void* d_ws, size_t ws_size,
                              hipStream_t stream) {
    const float* x     = (const float*)d_in[0];
    const float* gamma = (const float*)d_in[1];
    const float* beta  = (const float*)d_in[2];
    const float* wq = (const float*)d_in[3]; const float* bq = (const float*)d_in[4];
    const float* wk = (const float*)d_in[5]; const float* bk = (const float*)d_in[6];
    const float* wv = (const float*)d_in[7]; const float* bv = (const float*)d_in[8];
    const float* wp = (const float*)d_in[9]; const float* bp = (const float*)d_in[10];

    char* w = (char*)d_ws;
    size_t off = 0;
    auto take = [&](size_t bytes) -> void* {
        void* pp = w + off;
        off += (bytes + 255) & ~(size_t)255;
        return pp;
    };
    float2* pp = (float2*)take((size_t)B_ * G_ * 8 * sizeof(float2));  // 8 KB partials
    bf16* wqb = (bf16*)take((size_t)C_ * C_ * 2);
    bf16* wkb = (bf16*)take((size_t)C_ * C_ * 2);
    bf16* wvb = (bf16*)take((size_t)C_ * C_ * 2);
    bf16* wpb = (bf16*)take((size_t)C_ * C_ * 2);
    bf16* ht  = (bf16*)take((size_t)B_ * N_ * C_ * 2);  // [B,N,C]
    bf16* qt  = (bf16*)take((size_t)B_ * N_ * C_ * 2);  // [B,N,C]
    bf16* kt  = (bf16*)take((size_t)B_ * N_ * C_ * 2);  // [B,N,C]
    bf16* vv  = (bf16*)take((size_t)B_ * C_ * N_ * 2);  // [B,C,N]
    bf16* at  = ht;  // alias: ht dead after v-GEMM, at written by PV afterwards
    float* rowpart = (float*)take((size_t)B_ * N_ * 32 * 4);  // 2 MB row partials
    float* invsum  = (float*)take((size_t)B_ * N_ * 4);       // 64 KB

    // Tier A needs bf16 exp-scores for all batches beyond `off` so far.
    const bool tierA = (off + (size_t)B_ * N_ * N_ * 2 + 256) <= ws_size;

    gn_stats_part<<<dim3(8, B_ * G_), 256, 0, stream>>>(x, pp);
    gn_apply<<<dim3(N_ / 64, C_ / 64, B_), 256, 0, stream>>>(x, pp, gamma, beta, ht);
    f2b4<<<dim3(C_ * C_ / 4 / 256, 4), 256, 0, stream>>>(wq, wk, wv, wp, wqb, wkb, wvb, wpb,
                                                         C_ * C_ / 4);

    // q^T AND k^T in one dispatch (DUAL): 1024 blocks, GRIDSWAP walks rows.
    gemm_bt<4, 4, 0, 1, 0, 1, 0, 0, 1, 0>
        <<<dim3(B_ * N_ / 128, 2 * C_ / 128, 1), 256, 0, stream>>>(
        ht, wqb, qt, bq, nullptr, nullptr, nullptr, wkb, bk, kt,
        B_ * N_, C_, C_, 1.f, 0, 0, 0, 0);
    // v = Wv @ h : [C,N] per batch; 64x128 tile -> 8*32*4 = 1024 blocks
    gemm_bt<2, 4, 0, 2, 0, 0, 0, 0, 0, 0>
        <<<dim3(N_ / 128, C_ / 64, B_), 256, 0, stream>>>(
        wvb, ht, vv, bv, nullptr, nullptr, nullptr, nullptr, nullptr, nullptr,
        C_, N_, C_, 1.f, 0, (long)N_ * C_, (long)C_ * N_, 0);

    const float scl = 0.044194173824159216f;  // 1/sqrt(512)
    if (tierA) {
        bf16* sc = (bf16*)take((size_t)B_ * N_ * N_ * 2);
        // scores -> exp(scores) bf16 + row partial sums, all batches (4096 blocks)
        gemm_bt<4, 4, 0, 0, 0, 0, 1, 0, 0, 1>
            <<<dim3(N_ / 128, N_ / 128, B_), 256, 0, stream>>>(
            qt, kt, sc, nullptr, nullptr, rowpart, nullptr, nullptr, nullptr, nullptr,
            N_, N_, C_, scl, (long)N_ * C_, (long)N_ * C_, (long)N_ * N_, 0);
        rowinv<<<dim3(B_ * N_ / 256), 256, 0, stream>>>(rowpart, invsum, N_ / 128);
        // PV with fused 1/rowsum: 64x128 tile -> 64*4*4 = 1024 blocks (4/CU);
        // GRIDSWAP so exp-scores are fetched once
        gemm_bt<2, 4, 0, 0, 0, 1, 0, 1, 0, 1>
            <<<dim3(N_ / 64, C_ / 128, B_), 256, 0, stream>>>(
            sc, vv, at, nullptr, nullptr, nullptr, invsum, nullptr, nullptr, nullptr,
            N_, C_, N_, 1.f, (long)N_ * N_, (long)C_ * N_, (long)N_ * C_, 0);
    } else {
        bf16* sc = (bf16*)take((size_t)2 * N_ * N_ * 2);
        for (int p = 0; p < 2; ++p) {
            const long o2 = (long)p * 2 * N_ * C_;
            gemm_bt<4, 4, 0, 0, 0, 0, 1, 0, 0, 1>
                <<<dim3(N_ / 128, N_ / 128, 2), 256, 0, stream>>>(
                qt + o2, kt + o2, sc, nullptr, nullptr, rowpart, nullptr, nullptr,
                nullptr, nullptr, N_, N_, C_, scl,
                (long)N_ * C_, (long)N_ * C_, (long)N_ * N_, 0);
            rowinv<<<dim3(2 * N_ / 256), 256, 0, stream>>>(rowpart, invsum, N_ / 128);
            gemm_bt<2, 4, 0, 0, 0, 1, 0, 1, 0, 1>
                <<<dim3(N_ / 64, C_ / 128, 2), 256, 0, stream>>>(
                sc, vv + o2, at + o2, nullptr, nullptr, nullptr, invsum, nullptr,
                nullptr, nullptr, N_, C_, N_, 1.f,
                (long)N_ * N_, (long)C_ * N_, (long)N_ * C_, 0);
        }
    }
    // out = x + Wp @ a + bp : [C,N] per batch, 64x128 tile -> 1024 blocks
    gemm_bt<2, 4, 1, 2, 1, 0, 0, 0, 0, 0>
        <<<dim3(N_ / 128, C_ / 64, B_), 256, 0, stream>>>(
        wpb, at, d_out, bp, x, nullptr, nullptr, nullptr, nullptr, nullptr,
        C_, N_, C_, 1.f, 0, (long)N_ * C_, (long)C_ * N_, (long)C_ * N_);
}